// Round 8
// baseline (321.084 us; speedup 1.0000x reference)
//
#include <hip/hip_runtime.h>

typedef __bf16 bf16;
typedef __bf16 bf16x8 __attribute__((ext_vector_type(8)));
typedef float  f32x4  __attribute__((ext_vector_type(4)));

__device__ __forceinline__ void async16(const void* g, void* l) {
  __builtin_amdgcn_global_load_lds(
      (__attribute__((address_space(1))) void*)(g),
      (__attribute__((address_space(3))) void*)(l), 16, 0, 0);
}

__device__ __forceinline__ f32x4 mfma16(bf16x8 a, bf16x8 b, f32x4 c) {
  return __builtin_amdgcn_mfma_f32_16x16x32_bf16(a, b, c, 0, 0, 0);
}

// ---------------- hs f32 -> bf16 (float4 streaming) ---------------------------
__global__ __launch_bounds__(256) void cvt_hs_k(const float* __restrict__ src,
                                                bf16* __restrict__ dst, int n) {
  int i = (blockIdx.x * 256 + threadIdx.x) * 4;
  if (i + 3 < n) {
    float4 v = *(const float4*)(src + i);
    dst[i]     = (bf16)v.x;
    dst[i + 1] = (bf16)v.y;
    dst[i + 2] = (bf16)v.z;
    dst[i + 3] = (bf16)v.w;
  } else {
    for (int j = 0; j < 4 && i + j < n; ++j) dst[i + j] = (bf16)src[i + j];
  }
}

// ---------------- f32 transpose -> bf16: out[c][r] = (bf16)in[r][c] -----------
__global__ __launch_bounds__(256) void transpose_f32_k(const float* __restrict__ in,
                                                       bf16* __restrict__ out,
                                                       int R, int C) {
  __shared__ bf16 tile[32][33];
  int c0 = blockIdx.x * 32, r0 = blockIdx.y * 32;
  int t = threadIdx.x;
#pragma unroll
  for (int i = 0; i < 4; ++i) {
    int idx = t + i * 256;
    int r = idx >> 5, c = idx & 31;
    tile[r][c] = (bf16)in[(size_t)(r0 + r) * C + (c0 + c)];
  }
  __syncthreads();
#pragma unroll
  for (int i = 0; i < 4; ++i) {
    int idx = t + i * 256;
    int r = idx >> 5, c = idx & 31;
    out[(size_t)(c0 + r) * R + (r0 + c)] = tile[c][r];
  }
}

// ---------------- router stage 1: float4 partial sums over 64 rows of S -------
__global__ __launch_bounds__(256) void router_partial_k(const float* __restrict__ hs,
                                                        float* __restrict__ partial) {
  int b = blockIdx.x, g = blockIdx.y, t = threadIdx.x;
  if (t >= 192) return;
  const float* p = hs + ((size_t)b * 1024 + g * 64) * 768 + t * 4;
  float4 a = {0.f, 0.f, 0.f, 0.f};
  for (int s = 0; s < 64; ++s) {
    float4 v = *(const float4*)(p + (size_t)s * 768);
    a.x += v.x; a.y += v.y; a.z += v.z; a.w += v.w;
  }
  *(float4*)(partial + ((size_t)b * 16 + g) * 768 + t * 4) = a;
}

// ---------------- router stage 2: f32 mean -> logits -> top-6 mask ------------
__global__ __launch_bounds__(256) void router_final_k(const float* __restrict__ Wr,
                                                      const float* __restrict__ br,
                                                      const float* __restrict__ partial,
                                                      float* __restrict__ mask) {
  int b = blockIdx.x, t = threadIdx.x;
  __shared__ float mean_s[768];
  __shared__ float lg[12];
  for (int c = t; c < 768; c += 256) {
    float a = 0.f;
    for (int g = 0; g < 16; ++g) a += partial[((size_t)b * 16 + g) * 768 + c];
    mean_s[c] = a * (1.0f / 1024.0f);
  }
  __syncthreads();
  if (t < 12) {
    float a = br[t];
    for (int c = 0; c < 768; ++c) a += mean_s[c] * Wr[c * 12 + t];
    lg[t] = a;
  }
  __syncthreads();
  if (t == 0) {
    unsigned chosen = 0;
    for (int j = 0; j < 6; ++j) {
      int bi = -1; float bv = -1e30f;
      for (int h = 0; h < 12; ++h)
        if (!((chosen >> h) & 1) && lg[h] > bv) { bv = lg[h]; bi = h; }
      chosen |= 1u << bi;
    }
    for (int h = 0; h < 12; ++h) mask[b * 12 + h] = ((chosen >> h) & 1) ? 1.f : 0.f;
  }
}

// ------- fused QKV GEMM: A[M,768] x Wcat^T[2304,768], BK=64, swizzled LDS -----
__global__ __launch_bounds__(256) void gemm_qkv_k(
    const bf16* __restrict__ X, const bf16* __restrict__ Wcat,
    const float* __restrict__ bq, const float* __restrict__ bk, const float* __restrict__ bv,
    bf16* __restrict__ Qo, bf16* __restrict__ Ko, bf16* __restrict__ Vto) {
  __shared__ __align__(16) bf16 Al[128 * 64];
  __shared__ __align__(16) bf16 Bl[128 * 64];
  int bid = blockIdx.x;
  int xcd = bid & 7, idx = bid >> 3;
  int nt = idx % 18, mt8 = idx / 18;
  int m0 = (mt8 * 8 + xcd) * 128;
  int n0 = nt * 128;
  int z = nt / 6;
  int nb0 = n0 - z * 768;
  const float* bia = (z == 0) ? bq : (z == 1) ? bk : bv;
  int t = threadIdx.x, w = t >> 6, lane = t & 63, lrow = lane & 15, quad = lane >> 4;
  int wm = (w >> 1) * 64, wn = (w & 1) * 64;

  f32x4 acc[4][4];
#pragma unroll
  for (int a = 0; a < 4; ++a)
#pragma unroll
    for (int b = 0; b < 4; ++b) acc[a][b] = (f32x4){0.f, 0.f, 0.f, 0.f};

  for (int k0 = 0; k0 < 768; k0 += 64) {
#pragma unroll
    for (int i = 0; i < 4; ++i) {
      int c = i * 256 + t;
      int r = c >> 3, ch = (c & 7) ^ (r & 7);
      async16(X + (size_t)(m0 + r) * 768 + k0 + ch * 8, &Al[c * 8]);
    }
#pragma unroll
    for (int i = 0; i < 4; ++i) {
      int c = i * 256 + t;
      int r = c >> 3, ch = (c & 7) ^ (r & 7);
      async16(Wcat + (size_t)(n0 + r) * 768 + k0 + ch * 8, &Bl[c * 8]);
    }
    __syncthreads();
    bf16x8 af[2][4], bfr[2][4];
#pragma unroll
    for (int ks = 0; ks < 2; ++ks)
#pragma unroll
      for (int i = 0; i < 4; ++i) {
        int ra = wm + i * 16 + lrow;
        int rb = wn + i * 16 + lrow;
        af[ks][i]  = *(const bf16x8*)&Al[ra * 64 + (((ks * 4 + quad) ^ (ra & 7)) * 8)];
        bfr[ks][i] = *(const bf16x8*)&Bl[rb * 64 + (((ks * 4 + quad) ^ (rb & 7)) * 8)];
      }
#pragma unroll
    for (int ks = 0; ks < 2; ++ks)
#pragma unroll
      for (int mt = 0; mt < 4; ++mt)
#pragma unroll
        for (int nt2 = 0; nt2 < 4; ++nt2)
          acc[mt][nt2] = mfma16(af[ks][mt], bfr[ks][nt2], acc[mt][nt2]);
    __syncthreads();
  }

  float biasv[4];
#pragma unroll
  for (int nt2 = 0; nt2 < 4; ++nt2) biasv[nt2] = bia[nb0 + wn + nt2 * 16 + lrow];

#pragma unroll
  for (int mt = 0; mt < 4; ++mt)
#pragma unroll
    for (int nt2 = 0; nt2 < 4; ++nt2)
#pragma unroll
      for (int r = 0; r < 4; ++r) {
        int m = m0 + wm + mt * 16 + quad * 4 + r;
        int nl = nb0 + wn + nt2 * 16 + lrow;
        float v = acc[mt][nt2][r] + biasv[nt2];
        int bb = m >> 10, s = m & 1023, h = nl >> 6, d = nl & 63;
        if (z == 0)
          Qo[(((size_t)bb * 12 + h) * 1024 + s) * 64 + d] = (bf16)v;
        else if (z == 1)
          Ko[(((size_t)bb * 12 + h) * 1024 + s) * 64 + d] = (bf16)v;
        else
          Vto[(((size_t)bb * 12 + h) * 64 + d) * 1024 + s] = (bf16)v;
      }
}

// ---------------- flash attention, Q-tile = 64 rows ---------------------------
// grid (16, #bh). Each wave owns 16 q-rows. LDS 48 KB -> 3 blocks/CU.
__global__ __launch_bounds__(256) void attn_k(
    const bf16* __restrict__ Q, const bf16* __restrict__ K, const bf16* __restrict__ Vt,
    const float* __restrict__ mask, bf16* __restrict__ ctx) {
  int qt = blockIdx.x, bh = blockIdx.y;
  int b = bh / 12, h = bh % 12;
  int t = threadIdx.x, w = t >> 6, lane = t & 63, lrow = lane & 15, quad = lane >> 4;

  if (mask[bh] == 0.f) {  // masked head -> ctx = 0 for this 64-row q-tile
    for (int i = t; i < 2048; i += 256) {
      int r = i >> 5, c = i & 31;
      size_t e = ((size_t)(b * 1024 + qt * 64 + r)) * 768 + h * 64;
      ((unsigned*)ctx)[e / 2 + c] = 0u;
    }
    return;
  }

  __shared__ __align__(16) bf16 K_lds[128 * 64];     // [s][d] 16 KB
  __shared__ __align__(16) bf16 V_lds[64 * 128];     // [d][s] 16 KB
  __shared__ __align__(16) bf16 P_lds[4][16 * 128];  // per-wave 4 KB, tot 16 KB

  const bf16* Qh = Q  + (size_t)bh * 65536;
  const bf16* Kh = K  + (size_t)bh * 65536;
  const bf16* Vh = Vt + (size_t)bh * 65536;

  bf16x8 qf[2];
#pragma unroll
  for (int ks = 0; ks < 2; ++ks)
    qf[ks] = *(const bf16x8*)&Qh[(size_t)(qt * 64 + w * 16 + lrow) * 64 + ks * 32 + quad * 8];

  f32x4 o_acc[4];
  float m_i[4], l_i[4];
#pragma unroll
  for (int dt = 0; dt < 4; ++dt) o_acc[dt] = (f32x4){0.f, 0.f, 0.f, 0.f};
#pragma unroll
  for (int r = 0; r < 4; ++r) { m_i[r] = -INFINITY; l_i[r] = 0.f; }

  for (int kt = 0; kt < 8; ++kt) {
#pragma unroll
    for (int i = 0; i < 4; ++i) {
      int c = i * 256 + t;
      async16(Kh + (size_t)kt * 8192 + c * 8, &K_lds[c * 8]);
    }
#pragma unroll
    for (int i = 0; i < 4; ++i) {
      int c = i * 256 + t;
      async16(Vh + (size_t)(c >> 4) * 1024 + kt * 128 + (c & 15) * 8, &V_lds[c * 8]);
    }
    __syncthreads();

    // S = (Q K^T) * 0.125 : 16 q-rows x 128 k-cols per wave
    f32x4 s_acc[8];
#pragma unroll
    for (int nt = 0; nt < 8; ++nt) s_acc[nt] = (f32x4){0.f, 0.f, 0.f, 0.f};
#pragma unroll
    for (int nt = 0; nt < 8; ++nt)
#pragma unroll
      for (int ks = 0; ks < 2; ++ks) {
        bf16x8 kf = *(const bf16x8*)&K_lds[(nt * 16 + lrow) * 64 + ks * 32 + quad * 8];
        s_acc[nt] = mfma16(qf[ks], kf, s_acc[nt]);
      }
#pragma unroll
    for (int nt = 0; nt < 8; ++nt) s_acc[nt] = s_acc[nt] * 0.125f;

    // online softmax; write P (bf16) to per-wave LDS
#pragma unroll
    for (int r = 0; r < 4; ++r) {
      float mx = s_acc[0][r];
#pragma unroll
      for (int nt = 1; nt < 8; ++nt) mx = fmaxf(mx, s_acc[nt][r]);
      mx = fmaxf(mx, __shfl_xor(mx, 1));
      mx = fmaxf(mx, __shfl_xor(mx, 2));
      mx = fmaxf(mx, __shfl_xor(mx, 4));
      mx = fmaxf(mx, __shfl_xor(mx, 8));
      float mold = m_i[r];
      float mnew = fmaxf(mold, mx);
      float alpha = __expf(mold - mnew);
      m_i[r] = mnew;
      float rs = 0.f;
#pragma unroll
      for (int nt = 0; nt < 8; ++nt) {
        float pv = __expf(s_acc[nt][r] - mnew);
        rs += pv;
        P_lds[w][(quad * 4 + r) * 128 + nt * 16 + lrow] = (bf16)pv;
      }
      rs += __shfl_xor(rs, 1);
      rs += __shfl_xor(rs, 2);
      rs += __shfl_xor(rs, 4);
      rs += __shfl_xor(rs, 8);
      l_i[r] = l_i[r] * alpha + rs;
#pragma unroll
      for (int dt = 0; dt < 4; ++dt) o_acc[dt][r] *= alpha;
    }
    __syncthreads();

    // O += P V
#pragma unroll
    for (int dt = 0; dt < 4; ++dt)
#pragma unroll
      for (int ks = 0; ks < 4; ++ks) {
        bf16x8 vf = *(const bf16x8*)&V_lds[(dt * 16 + lrow) * 128 + ks * 32 + quad * 8];
        bf16x8 pf = *(const bf16x8*)&P_lds[w][lrow * 128 + ks * 32 + quad * 8];
        o_acc[dt] = mfma16(pf, vf, o_acc[dt]);
      }
    __syncthreads();
  }

  // epilogue: O / l -> ctx[b][s][h*64+d]
#pragma unroll
  for (int r = 0; r < 4; ++r) {
    float inv = 1.0f / l_i[r];
    int s = qt * 64 + w * 16 + quad * 4 + r;
#pragma unroll
    for (int dt = 0; dt < 4; ++dt) {
      int d = dt * 16 + lrow;
      ctx[((size_t)(b * 1024 + s)) * 768 + h * 64 + d] = (bf16)(o_acc[dt][r] * inv);
    }
  }
}

// ------- out-proj GEMM: BK=64, swizzled LDS, XCD swizzle; +bias+residual ------
__global__ __launch_bounds__(256) void gemm_out_k(
    const bf16* __restrict__ Cx, const bf16* __restrict__ Wot,
    const float* __restrict__ bo, const float* __restrict__ res,
    float* __restrict__ xo) {
  __shared__ __align__(16) bf16 Al[128 * 64];
  __shared__ __align__(16) bf16 Bl[128 * 64];
  int bid = blockIdx.x;
  int xcd = bid & 7, idx = bid >> 3;
  int nt = idx % 6, mt8 = idx / 6;
  int m0 = (mt8 * 8 + xcd) * 128;
  int n0 = nt * 128;
  int t = threadIdx.x, w = t >> 6, lane = t & 63, lrow = lane & 15, quad = lane >> 4;
  int wm = (w >> 1) * 64, wn = (w & 1) * 64;

  f32x4 acc[4][4];
#pragma unroll
  for (int a = 0; a < 4; ++a)
#pragma unroll
    for (int b = 0; b < 4; ++b) acc[a][b] = (f32x4){0.f, 0.f, 0.f, 0.f};

  for (int k0 = 0; k0 < 768; k0 += 64) {
#pragma unroll
    for (int i = 0; i < 4; ++i) {
      int c = i * 256 + t;
      int r = c >> 3, ch = (c & 7) ^ (r & 7);
      async16(Cx + (size_t)(m0 + r) * 768 + k0 + ch * 8, &Al[c * 8]);
    }
#pragma unroll
    for (int i = 0; i < 4; ++i) {
      int c = i * 256 + t;
      int r = c >> 3, ch = (c & 7) ^ (r & 7);
      async16(Wot + (size_t)(n0 + r) * 768 + k0 + ch * 8, &Bl[c * 8]);
    }
    __syncthreads();
    bf16x8 af[2][4], bfr[2][4];
#pragma unroll
    for (int ks = 0; ks < 2; ++ks)
#pragma unroll
      for (int i = 0; i < 4; ++i) {
        int ra = wm + i * 16 + lrow;
        int rb = wn + i * 16 + lrow;
        af[ks][i]  = *(const bf16x8*)&Al[ra * 64 + (((ks * 4 + quad) ^ (ra & 7)) * 8)];
        bfr[ks][i] = *(const bf16x8*)&Bl[rb * 64 + (((ks * 4 + quad) ^ (rb & 7)) * 8)];
      }
#pragma unroll
    for (int ks = 0; ks < 2; ++ks)
#pragma unroll
      for (int mt = 0; mt < 4; ++mt)
#pragma unroll
        for (int nt2 = 0; nt2 < 4; ++nt2)
          acc[mt][nt2] = mfma16(af[ks][mt], bfr[ks][nt2], acc[mt][nt2]);
    __syncthreads();
  }

  float biasv[4];
#pragma unroll
  for (int nt2 = 0; nt2 < 4; ++nt2) biasv[nt2] = bo[n0 + wn + nt2 * 16 + lrow];

#pragma unroll
  for (int mt = 0; mt < 4; ++mt)
#pragma unroll
    for (int nt2 = 0; nt2 < 4; ++nt2)
#pragma unroll
      for (int r = 0; r < 4; ++r) {
        int m = m0 + wm + mt * 16 + quad * 4 + r;
        int n = n0 + wn + nt2 * 16 + lrow;
        xo[(size_t)m * 768 + n] = acc[mt][nt2][r] + biasv[nt2] + res[(size_t)m * 768 + n];
      }
}

// ---------------- LayerNorm over hid=768 per row (f32 in, f32 out) ------------
__global__ __launch_bounds__(256) void ln_k(const float* __restrict__ x,
                                            const float* __restrict__ g,
                                            const float* __restrict__ be,
                                            float* __restrict__ out) {
  int row = blockIdx.x, t = threadIdx.x;
  const float* xr = x + (size_t)row * 768;
  float v0 = xr[t], v1 = xr[t + 256], v2 = xr[t + 512];
  float s = v0 + v1 + v2;
  float s2 = v0 * v0 + v1 * v1 + v2 * v2;
#pragma unroll
  for (int off = 32; off > 0; off >>= 1) {
    s  += __shfl_down(s, off);
    s2 += __shfl_down(s2, off);
  }
  __shared__ float red[8];
  if ((t & 63) == 0) { red[(t >> 6) * 2] = s; red[(t >> 6) * 2 + 1] = s2; }
  __syncthreads();
  if (t == 0) {
    float a = 0.f, b2 = 0.f;
    for (int i = 0; i < 4; ++i) { a += red[2 * i]; b2 += red[2 * i + 1]; }
    float mu = a * (1.0f / 768.0f);
    float var = b2 * (1.0f / 768.0f) - mu * mu;
    red[0] = mu;
    red[1] = rsqrtf(var + 1e-12f);
  }
  __syncthreads();
  float mu = red[0], rs = red[1];
  out[(size_t)row * 768 + t]       = (v0 - mu) * rs * g[t]       + be[t];
  out[(size_t)row * 768 + t + 256] = (v1 - mu) * rs * g[t + 256] + be[t + 256];
  out[(size_t)row * 768 + t + 512] = (v2 - mu) * rs * g[t + 512] + be[t + 512];
}

// ---------------- host launcher ----------------------------------------------
extern "C" void kernel_launch(void* const* d_in, const int* in_sizes, int n_in,
                              void* d_out, int out_size, void* d_ws, size_t ws_size,
                              hipStream_t stream) {
  const float* hs  = (const float*)d_in[0];
  const float* Wq  = (const float*)d_in[1];
  const float* bq  = (const float*)d_in[2];
  const float* Wk  = (const float*)d_in[3];
  const float* bk  = (const float*)d_in[4];
  const float* Wv  = (const float*)d_in[5];
  const float* bv  = (const float*)d_in[6];
  const float* Wr  = (const float*)d_in[7];
  const float* br  = (const float*)d_in[8];
  const float* Wo  = (const float*)d_in[9];
  const float* bo  = (const float*)d_in[10];
  const float* lng = (const float*)d_in[11];
  const float* lnb = (const float*)d_in[12];
  float* out = (float*)d_out;
  dim3 blk(256);

  // ---- workspace layout ----
  char* p = (char*)d_ws;
  float* maskp   = (float*)p; p += 512;
  float* partial = (float*)p; p += (size_t)8 * 16 * 768 * 4;   // 384 KB
  bf16* hsb  = (bf16*)p; p += (size_t)8192 * 768 * 2;          // 12.6 MB
  bf16* Wcat = (bf16*)p; p += (size_t)2304 * 768 * 2;          // 3.5 MB
  bf16* Wot  = (bf16*)p; p += (size_t)768 * 768 * 2;           // 1.2 MB

  cvt_hs_k<<<dim3(6144), blk, 0, stream>>>(hs, hsb, 6291456);
  transpose_f32_k<<<dim3(24, 24), blk, 0, stream>>>(Wq, Wcat,              768, 768);
  transpose_f32_k<<<dim3(24, 24), blk, 0, stream>>>(Wk, Wcat + 768 * 768,  768, 768);
  transpose_f32_k<<<dim3(24, 24), blk, 0, stream>>>(Wv, Wcat + 1536 * 768, 768, 768);
  transpose_f32_k<<<dim3(24, 24), blk, 0, stream>>>(Wo, Wot, 768, 768);
  router_partial_k<<<dim3(8, 16), blk, 0, stream>>>(hs, partial);
  router_final_k<<<dim3(8), blk, 0, stream>>>(Wr, br, partial, maskp);

  size_t used_common = (size_t)(p - (char*)d_ws);
  size_t need_big = used_common + 3 * (size_t)8192 * 768 * 2;

  if (ws_size >= need_big) {
    char* qk_base = p;
    bf16* Qb  = (bf16*)p; p += (size_t)8192 * 768 * 2;
    bf16* Kb  = (bf16*)p; p += (size_t)8192 * 768 * 2;
    bf16* Vtb = (bf16*)p;
    float* Xb = (float*)qk_base;   // aliases Qb+Kb (dead after attn)
    bf16* Ctx = (bf16*)d_out;      // parks in d_out; ln_k overwrites all

    gemm_qkv_k<<<dim3(8 * 8 * 18), blk, 0, stream>>>(hsb, Wcat, bq, bk, bv, Qb, Kb, Vtb);
    attn_k<<<dim3(16, 96), blk, 0, stream>>>(Qb, Kb, Vtb, maskp, Ctx);
    gemm_out_k<<<dim3(8 * 8 * 6), blk, 0, stream>>>(Ctx, Wot, bo, hs, Xb);
    ln_k<<<dim3(8192), blk, 0, stream>>>(Xb, lng, lnb, out);
  } else {
    bf16* Qb  = (bf16*)p; p += (size_t)1024 * 768 * 2;
    bf16* Kb  = (bf16*)p; p += (size_t)1024 * 768 * 2;
    bf16* Vtb = (bf16*)p; p += (size_t)1024 * 768 * 2;
    bf16* Ctx = (bf16*)p; p += (size_t)1024 * 768 * 2;
    float* Xb = (float*)p; p += (size_t)1024 * 768 * 4;

    for (int b = 0; b < 8; ++b) {
      const bf16* hsb_b = hsb + (size_t)b * 1024 * 768;
      const float* hs_b = hs + (size_t)b * 1024 * 768;
      float* outb = out + (size_t)b * 1024 * 768;
      gemm_qkv_k<<<dim3(8 * 1 * 18), blk, 0, stream>>>(hsb_b, Wcat, bq, bk, bv, Qb, Kb, Vtb);
      attn_k<<<dim3(16, 12), blk, 0, stream>>>(Qb, Kb, Vtb, maskp + b * 12, Ctx);
      gemm_out_k<<<dim3(8 * 1 * 6), blk, 0, stream>>>(Ctx, Wot, bo, hs_b, Xb);
      ln_k<<<dim3(1024), blk, 0, stream>>>(Xb, lng, lnb, outb);
    }
  }
}

// Round 9
// 285.851 us; speedup vs baseline: 1.1233x; 1.1233x over previous
//
#include <hip/hip_runtime.h>

typedef __bf16 bf16;
typedef __bf16 bf16x8 __attribute__((ext_vector_type(8)));
typedef float  f32x4  __attribute__((ext_vector_type(4)));

__device__ __forceinline__ void async16(const void* g, void* l) {
  __builtin_amdgcn_global_load_lds(
      (__attribute__((address_space(1))) void*)(g),
      (__attribute__((address_space(3))) void*)(l), 16, 0, 0);
}

__device__ __forceinline__ f32x4 mfma16(bf16x8 a, bf16x8 b, f32x4 c) {
  return __builtin_amdgcn_mfma_f32_16x16x32_bf16(a, b, c, 0, 0, 0);
}

// ---------------- hs f32 -> bf16 (float4 streaming) ---------------------------
__global__ __launch_bounds__(256) void cvt_hs_k(const float* __restrict__ src,
                                                bf16* __restrict__ dst, int n) {
  int i = (blockIdx.x * 256 + threadIdx.x) * 4;
  if (i + 3 < n) {
    float4 v = *(const float4*)(src + i);
    dst[i]     = (bf16)v.x;
    dst[i + 1] = (bf16)v.y;
    dst[i + 2] = (bf16)v.z;
    dst[i + 3] = (bf16)v.w;
  } else {
    for (int j = 0; j < 4 && i + j < n; ++j) dst[i + j] = (bf16)src[i + j];
  }
}

// ---------------- f32 transpose -> bf16: out[c][r] = (bf16)in[r][c] -----------
__global__ __launch_bounds__(256) void transpose_f32_k(const float* __restrict__ in,
                                                       bf16* __restrict__ out,
                                                       int R, int C) {
  __shared__ bf16 tile[32][33];
  int c0 = blockIdx.x * 32, r0 = blockIdx.y * 32;
  int t = threadIdx.x;
#pragma unroll
  for (int i = 0; i < 4; ++i) {
    int idx = t + i * 256;
    int r = idx >> 5, c = idx & 31;
    tile[r][c] = (bf16)in[(size_t)(r0 + r) * C + (c0 + c)];
  }
  __syncthreads();
#pragma unroll
  for (int i = 0; i < 4; ++i) {
    int idx = t + i * 256;
    int r = idx >> 5, c = idx & 31;
    out[(size_t)(c0 + r) * R + (r0 + c)] = tile[c][r];
  }
}

// ---------------- router stage 1: float4 partial sums over 64 rows of S -------
__global__ __launch_bounds__(256) void router_partial_k(const float* __restrict__ hs,
                                                        float* __restrict__ partial) {
  int b = blockIdx.x, g = blockIdx.y, t = threadIdx.x;
  if (t >= 192) return;
  const float* p = hs + ((size_t)b * 1024 + g * 64) * 768 + t * 4;
  float4 a = {0.f, 0.f, 0.f, 0.f};
  for (int s = 0; s < 64; ++s) {
    float4 v = *(const float4*)(p + (size_t)s * 768);
    a.x += v.x; a.y += v.y; a.z += v.z; a.w += v.w;
  }
  *(float4*)(partial + ((size_t)b * 16 + g) * 768 + t * 4) = a;
}

// ---------------- router stage 2: f32 mean -> logits -> top-6 mask ------------
__global__ __launch_bounds__(256) void router_final_k(const float* __restrict__ Wr,
                                                      const float* __restrict__ br,
                                                      const float* __restrict__ partial,
                                                      float* __restrict__ mask) {
  int b = blockIdx.x, t = threadIdx.x;
  __shared__ float mean_s[768];
  __shared__ float lg[12];
  for (int c = t; c < 768; c += 256) {
    float a = 0.f;
    for (int g = 0; g < 16; ++g) a += partial[((size_t)b * 16 + g) * 768 + c];
    mean_s[c] = a * (1.0f / 1024.0f);
  }
  __syncthreads();
  if (t < 12) {
    float a = br[t];
    for (int c = 0; c < 768; ++c) a += mean_s[c] * Wr[c * 12 + t];
    lg[t] = a;
  }
  __syncthreads();
  if (t == 0) {
    unsigned chosen = 0;
    for (int j = 0; j < 6; ++j) {
      int bi = -1; float bv = -1e30f;
      for (int h = 0; h < 12; ++h)
        if (!((chosen >> h) & 1) && lg[h] > bv) { bv = lg[h]; bi = h; }
      chosen |= 1u << bi;
    }
    for (int h = 0; h < 12; ++h) mask[b * 12 + h] = ((chosen >> h) & 1) ? 1.f : 0.f;
  }
}

// ------- fused QKV GEMM: A[M,768] x Wcat^T[2304,768], BK=64, swizzled LDS -----
__global__ __launch_bounds__(256) void gemm_qkv_k(
    const bf16* __restrict__ X, const bf16* __restrict__ Wcat,
    const float* __restrict__ bq, const float* __restrict__ bk, const float* __restrict__ bv,
    bf16* __restrict__ Qo, bf16* __restrict__ Ko, bf16* __restrict__ Vto) {
  __shared__ __align__(16) bf16 Al[128 * 64];
  __shared__ __align__(16) bf16 Bl[128 * 64];
  int bid = blockIdx.x;
  int xcd = bid & 7, idx = bid >> 3;
  int nt = idx % 18, mt8 = idx / 18;
  int m0 = (mt8 * 8 + xcd) * 128;
  int n0 = nt * 128;
  int z = nt / 6;
  int nb0 = n0 - z * 768;
  const float* bia = (z == 0) ? bq : (z == 1) ? bk : bv;
  int t = threadIdx.x, w = t >> 6, lane = t & 63, lrow = lane & 15, quad = lane >> 4;
  int wm = (w >> 1) * 64, wn = (w & 1) * 64;

  f32x4 acc[4][4];
#pragma unroll
  for (int a = 0; a < 4; ++a)
#pragma unroll
    for (int b = 0; b < 4; ++b) acc[a][b] = (f32x4){0.f, 0.f, 0.f, 0.f};

  for (int k0 = 0; k0 < 768; k0 += 64) {
#pragma unroll
    for (int i = 0; i < 4; ++i) {
      int c = i * 256 + t;
      int r = c >> 3, ch = (c & 7) ^ (r & 7);
      async16(X + (size_t)(m0 + r) * 768 + k0 + ch * 8, &Al[c * 8]);
    }
#pragma unroll
    for (int i = 0; i < 4; ++i) {
      int c = i * 256 + t;
      int r = c >> 3, ch = (c & 7) ^ (r & 7);
      async16(Wcat + (size_t)(n0 + r) * 768 + k0 + ch * 8, &Bl[c * 8]);
    }
    __syncthreads();
    bf16x8 af[2][4], bfr[2][4];
#pragma unroll
    for (int ks = 0; ks < 2; ++ks)
#pragma unroll
      for (int i = 0; i < 4; ++i) {
        int ra = wm + i * 16 + lrow;
        int rb = wn + i * 16 + lrow;
        af[ks][i]  = *(const bf16x8*)&Al[ra * 64 + (((ks * 4 + quad) ^ (ra & 7)) * 8)];
        bfr[ks][i] = *(const bf16x8*)&Bl[rb * 64 + (((ks * 4 + quad) ^ (rb & 7)) * 8)];
      }
#pragma unroll
    for (int ks = 0; ks < 2; ++ks)
#pragma unroll
      for (int mt = 0; mt < 4; ++mt)
#pragma unroll
        for (int nt2 = 0; nt2 < 4; ++nt2)
          acc[mt][nt2] = mfma16(af[ks][mt], bfr[ks][nt2], acc[mt][nt2]);
    __syncthreads();
  }

  float biasv[4];
#pragma unroll
  for (int nt2 = 0; nt2 < 4; ++nt2) biasv[nt2] = bia[nb0 + wn + nt2 * 16 + lrow];

#pragma unroll
  for (int mt = 0; mt < 4; ++mt)
#pragma unroll
    for (int nt2 = 0; nt2 < 4; ++nt2)
#pragma unroll
      for (int r = 0; r < 4; ++r) {
        int m = m0 + wm + mt * 16 + quad * 4 + r;
        int nl = nb0 + wn + nt2 * 16 + lrow;
        float v = acc[mt][nt2][r] + biasv[nt2];
        int bb = m >> 10, s = m & 1023, h = nl >> 6, d = nl & 63;
        if (z == 0)
          Qo[(((size_t)bb * 12 + h) * 1024 + s) * 64 + d] = (bf16)v;
        else if (z == 1)
          Ko[(((size_t)bb * 12 + h) * 1024 + s) * 64 + d] = (bf16)v;
        else
          Vto[(((size_t)bb * 12 + h) * 64 + d) * 1024 + s] = (bf16)v;
      }
}

// ---------------- flash attention, Q-tile=128, XOR-swizzled LDS ---------------
// K_lds/V_lds: chunk-XOR swizzle (as in GEMMs). P_lds: row stride 136 (padded).
__global__ __launch_bounds__(256) void attn_k(
    const bf16* __restrict__ Q, const bf16* __restrict__ K, const bf16* __restrict__ Vt,
    const float* __restrict__ mask, bf16* __restrict__ ctx) {
  int qt = blockIdx.x, bh = blockIdx.y;
  int b = bh / 12, h = bh % 12;
  int t = threadIdx.x, w = t >> 6, lane = t & 63, lrow = lane & 15, quad = lane >> 4;

  if (mask[bh] == 0.f) {  // masked head -> ctx = 0 for this q-tile
    for (int i = t; i < 4096; i += 256) {
      int r = i >> 5, c = i & 31;
      size_t e = ((size_t)(b * 1024 + qt * 128 + r)) * 768 + h * 64;
      ((unsigned*)ctx)[e / 2 + c] = 0u;
    }
    return;
  }

  __shared__ __align__(16) bf16 K_lds[128 * 64];      // [s][d], swizzled chunks
  __shared__ __align__(16) bf16 V_lds[64 * 128];      // [d][s], swizzled chunks
  __shared__ __align__(16) bf16 P_lds[4][32 * 136];   // per-wave, stride 136

  const bf16* Qh = Q  + (size_t)bh * 65536;
  const bf16* Kh = K  + (size_t)bh * 65536;
  const bf16* Vh = Vt + (size_t)bh * 65536;

  bf16x8 qf[2][2];
#pragma unroll
  for (int mt = 0; mt < 2; ++mt)
#pragma unroll
    for (int ks = 0; ks < 2; ++ks)
      qf[mt][ks] = *(const bf16x8*)&Qh[(size_t)(qt * 128 + w * 32 + mt * 16 + lrow) * 64 + ks * 32 + quad * 8];

  f32x4 o_acc[2][4];
  float m_i[2][4], l_i[2][4];
#pragma unroll
  for (int mt = 0; mt < 2; ++mt) {
#pragma unroll
    for (int dt = 0; dt < 4; ++dt) o_acc[mt][dt] = (f32x4){0.f, 0.f, 0.f, 0.f};
#pragma unroll
    for (int r = 0; r < 4; ++r) { m_i[mt][r] = -INFINITY; l_i[mt][r] = 0.f; }
  }

  for (int kt = 0; kt < 8; ++kt) {
#pragma unroll
    for (int i = 0; i < 4; ++i) {  // K tile, source-chunk swizzled
      int c = i * 256 + t;
      int r = c >> 3, ch = (c & 7) ^ (r & 7);
      async16(Kh + (size_t)kt * 8192 + r * 64 + ch * 8, &K_lds[c * 8]);
    }
#pragma unroll
    for (int i = 0; i < 4; ++i) {  // V^T tile, source-chunk swizzled
      int c = i * 256 + t;
      int r = c >> 4, ch = (c & 15) ^ (r & 7);
      async16(Vh + (size_t)r * 1024 + kt * 128 + ch * 8, &V_lds[c * 8]);
    }
    __syncthreads();

    // S = (Q K^T) * 0.125
    f32x4 s_acc[2][8];
#pragma unroll
    for (int mt = 0; mt < 2; ++mt)
#pragma unroll
      for (int nt = 0; nt < 8; ++nt) s_acc[mt][nt] = (f32x4){0.f, 0.f, 0.f, 0.f};
#pragma unroll
    for (int nt = 0; nt < 8; ++nt) {
      int rb = nt * 16 + lrow;
#pragma unroll
      for (int ks = 0; ks < 2; ++ks) {
        bf16x8 kf = *(const bf16x8*)&K_lds[rb * 64 + (((ks * 4 + quad) ^ (rb & 7)) * 8)];
        s_acc[0][nt] = mfma16(qf[0][ks], kf, s_acc[0][nt]);
        s_acc[1][nt] = mfma16(qf[1][ks], kf, s_acc[1][nt]);
      }
    }
#pragma unroll
    for (int mt = 0; mt < 2; ++mt)
#pragma unroll
      for (int nt = 0; nt < 8; ++nt) s_acc[mt][nt] = s_acc[mt][nt] * 0.125f;

    // online softmax; write P (bf16) to per-wave padded LDS
#pragma unroll
    for (int mt = 0; mt < 2; ++mt) {
#pragma unroll
      for (int r = 0; r < 4; ++r) {
        float mx = s_acc[mt][0][r];
#pragma unroll
        for (int nt = 1; nt < 8; ++nt) mx = fmaxf(mx, s_acc[mt][nt][r]);
        mx = fmaxf(mx, __shfl_xor(mx, 1));
        mx = fmaxf(mx, __shfl_xor(mx, 2));
        mx = fmaxf(mx, __shfl_xor(mx, 4));
        mx = fmaxf(mx, __shfl_xor(mx, 8));
        float mold = m_i[mt][r];
        float mnew = fmaxf(mold, mx);
        float alpha = __expf(mold - mnew);
        m_i[mt][r] = mnew;
        float rs = 0.f;
#pragma unroll
        for (int nt = 0; nt < 8; ++nt) {
          float pv = __expf(s_acc[mt][nt][r] - mnew);
          rs += pv;
          P_lds[w][(mt * 16 + quad * 4 + r) * 136 + nt * 16 + lrow] = (bf16)pv;
        }
        rs += __shfl_xor(rs, 1);
        rs += __shfl_xor(rs, 2);
        rs += __shfl_xor(rs, 4);
        rs += __shfl_xor(rs, 8);
        l_i[mt][r] = l_i[mt][r] * alpha + rs;
#pragma unroll
        for (int dt = 0; dt < 4; ++dt) o_acc[mt][dt][r] *= alpha;
      }
    }
    __syncthreads();

    // O += P V
#pragma unroll
    for (int dt = 0; dt < 4; ++dt) {
      int rv = dt * 16 + lrow;
#pragma unroll
      for (int ks = 0; ks < 4; ++ks) {
        bf16x8 vf = *(const bf16x8*)&V_lds[rv * 128 + (((ks * 4 + quad) ^ (rv & 7)) * 8)];
#pragma unroll
        for (int mt = 0; mt < 2; ++mt) {
          bf16x8 pf = *(const bf16x8*)&P_lds[w][(mt * 16 + lrow) * 136 + ks * 32 + quad * 8];
          o_acc[mt][dt] = mfma16(pf, vf, o_acc[mt][dt]);
        }
      }
    }
    __syncthreads();
  }

  // epilogue: O / l -> ctx[b][s][h*64+d]
#pragma unroll
  for (int mt = 0; mt < 2; ++mt)
#pragma unroll
    for (int r = 0; r < 4; ++r) {
      float inv = 1.0f / l_i[mt][r];
      int s = qt * 128 + w * 32 + mt * 16 + quad * 4 + r;
#pragma unroll
      for (int dt = 0; dt < 4; ++dt) {
        int d = dt * 16 + lrow;
        ctx[((size_t)(b * 1024 + s)) * 768 + h * 64 + d] = (bf16)(o_acc[mt][dt][r] * inv);
      }
    }
}

// ------- out-proj GEMM: BK=64, swizzled LDS, XCD swizzle; +bias+residual ------
__global__ __launch_bounds__(256) void gemm_out_k(
    const bf16* __restrict__ Cx, const bf16* __restrict__ Wot,
    const float* __restrict__ bo, const float* __restrict__ res,
    float* __restrict__ xo) {
  __shared__ __align__(16) bf16 Al[128 * 64];
  __shared__ __align__(16) bf16 Bl[128 * 64];
  int bid = blockIdx.x;
  int xcd = bid & 7, idx = bid >> 3;
  int nt = idx % 6, mt8 = idx / 6;
  int m0 = (mt8 * 8 + xcd) * 128;
  int n0 = nt * 128;
  int t = threadIdx.x, w = t >> 6, lane = t & 63, lrow = lane & 15, quad = lane >> 4;
  int wm = (w >> 1) * 64, wn = (w & 1) * 64;

  f32x4 acc[4][4];
#pragma unroll
  for (int a = 0; a < 4; ++a)
#pragma unroll
    for (int b = 0; b < 4; ++b) acc[a][b] = (f32x4){0.f, 0.f, 0.f, 0.f};

  for (int k0 = 0; k0 < 768; k0 += 64) {
#pragma unroll
    for (int i = 0; i < 4; ++i) {
      int c = i * 256 + t;
      int r = c >> 3, ch = (c & 7) ^ (r & 7);
      async16(Cx + (size_t)(m0 + r) * 768 + k0 + ch * 8, &Al[c * 8]);
    }
#pragma unroll
    for (int i = 0; i < 4; ++i) {
      int c = i * 256 + t;
      int r = c >> 3, ch = (c & 7) ^ (r & 7);
      async16(Wot + (size_t)(n0 + r) * 768 + k0 + ch * 8, &Bl[c * 8]);
    }
    __syncthreads();
    bf16x8 af[2][4], bfr[2][4];
#pragma unroll
    for (int ks = 0; ks < 2; ++ks)
#pragma unroll
      for (int i = 0; i < 4; ++i) {
        int ra = wm + i * 16 + lrow;
        int rb = wn + i * 16 + lrow;
        af[ks][i]  = *(const bf16x8*)&Al[ra * 64 + (((ks * 4 + quad) ^ (ra & 7)) * 8)];
        bfr[ks][i] = *(const bf16x8*)&Bl[rb * 64 + (((ks * 4 + quad) ^ (rb & 7)) * 8)];
      }
#pragma unroll
    for (int ks = 0; ks < 2; ++ks)
#pragma unroll
      for (int mt = 0; mt < 4; ++mt)
#pragma unroll
        for (int nt2 = 0; nt2 < 4; ++nt2)
          acc[mt][nt2] = mfma16(af[ks][mt], bfr[ks][nt2], acc[mt][nt2]);
    __syncthreads();
  }

  float biasv[4];
#pragma unroll
  for (int nt2 = 0; nt2 < 4; ++nt2) biasv[nt2] = bo[n0 + wn + nt2 * 16 + lrow];

#pragma unroll
  for (int mt = 0; mt < 4; ++mt)
#pragma unroll
    for (int nt2 = 0; nt2 < 4; ++nt2)
#pragma unroll
      for (int r = 0; r < 4; ++r) {
        int m = m0 + wm + mt * 16 + quad * 4 + r;
        int n = n0 + wn + nt2 * 16 + lrow;
        xo[(size_t)m * 768 + n] = acc[mt][nt2][r] + biasv[nt2] + res[(size_t)m * 768 + n];
      }
}

// ---------------- LayerNorm over hid=768 per row (f32 in, f32 out) ------------
__global__ __launch_bounds__(256) void ln_k(const float* __restrict__ x,
                                            const float* __restrict__ g,
                                            const float* __restrict__ be,
                                            float* __restrict__ out) {
  int row = blockIdx.x, t = threadIdx.x;
  const float* xr = x + (size_t)row * 768;
  float v0 = xr[t], v1 = xr[t + 256], v2 = xr[t + 512];
  float s = v0 + v1 + v2;
  float s2 = v0 * v0 + v1 * v1 + v2 * v2;
#pragma unroll
  for (int off = 32; off > 0; off >>= 1) {
    s  += __shfl_down(s, off);
    s2 += __shfl_down(s2, off);
  }
  __shared__ float red[8];
  if ((t & 63) == 0) { red[(t >> 6) * 2] = s; red[(t >> 6) * 2 + 1] = s2; }
  __syncthreads();
  if (t == 0) {
    float a = 0.f, b2 = 0.f;
    for (int i = 0; i < 4; ++i) { a += red[2 * i]; b2 += red[2 * i + 1]; }
    float mu = a * (1.0f / 768.0f);
    float var = b2 * (1.0f / 768.0f) - mu * mu;
    red[0] = mu;
    red[1] = rsqrtf(var + 1e-12f);
  }
  __syncthreads();
  float mu = red[0], rs = red[1];
  out[(size_t)row * 768 + t]       = (v0 - mu) * rs * g[t]       + be[t];
  out[(size_t)row * 768 + t + 256] = (v1 - mu) * rs * g[t + 256] + be[t + 256];
  out[(size_t)row * 768 + t + 512] = (v2 - mu) * rs * g[t + 512] + be[t + 512];
}

// ---------------- host launcher ----------------------------------------------
extern "C" void kernel_launch(void* const* d_in, const int* in_sizes, int n_in,
                              void* d_out, int out_size, void* d_ws, size_t ws_size,
                              hipStream_t stream) {
  const float* hs  = (const float*)d_in[0];
  const float* Wq  = (const float*)d_in[1];
  const float* bq  = (const float*)d_in[2];
  const float* Wk  = (const float*)d_in[3];
  const float* bk  = (const float*)d_in[4];
  const float* Wv  = (const float*)d_in[5];
  const float* bv  = (const float*)d_in[6];
  const float* Wr  = (const float*)d_in[7];
  const float* br  = (const float*)d_in[8];
  const float* Wo  = (const float*)d_in[9];
  const float* bo  = (const float*)d_in[10];
  const float* lng = (const float*)d_in[11];
  const float* lnb = (const float*)d_in[12];
  float* out = (float*)d_out;
  dim3 blk(256);

  // ---- workspace layout ----
  char* p = (char*)d_ws;
  float* maskp   = (float*)p; p += 512;
  float* partial = (float*)p; p += (size_t)8 * 16 * 768 * 4;   // 384 KB
  bf16* hsb  = (bf16*)p; p += (size_t)8192 * 768 * 2;          // 12.6 MB
  bf16* Wcat = (bf16*)p; p += (size_t)2304 * 768 * 2;          // 3.5 MB
  bf16* Wot  = (bf16*)p; p += (size_t)768 * 768 * 2;           // 1.2 MB

  cvt_hs_k<<<dim3(6144), blk, 0, stream>>>(hs, hsb, 6291456);
  transpose_f32_k<<<dim3(24, 24), blk, 0, stream>>>(Wq, Wcat,              768, 768);
  transpose_f32_k<<<dim3(24, 24), blk, 0, stream>>>(Wk, Wcat + 768 * 768,  768, 768);
  transpose_f32_k<<<dim3(24, 24), blk, 0, stream>>>(Wv, Wcat + 1536 * 768, 768, 768);
  transpose_f32_k<<<dim3(24, 24), blk, 0, stream>>>(Wo, Wot, 768, 768);
  router_partial_k<<<dim3(8, 16), blk, 0, stream>>>(hs, partial);
  router_final_k<<<dim3(8), blk, 0, stream>>>(Wr, br, partial, maskp);

  size_t used_common = (size_t)(p - (char*)d_ws);
  size_t need_big = used_common + 3 * (size_t)8192 * 768 * 2;

  if (ws_size >= need_big) {
    char* qk_base = p;
    bf16* Qb  = (bf16*)p; p += (size_t)8192 * 768 * 2;
    bf16* Kb  = (bf16*)p; p += (size_t)8192 * 768 * 2;
    bf16* Vtb = (bf16*)p;
    float* Xb = (float*)qk_base;   // aliases Qb+Kb (dead after attn)
    bf16* Ctx = (bf16*)d_out;      // parks in d_out; ln_k overwrites all

    gemm_qkv_k<<<dim3(8 * 8 * 18), blk, 0, stream>>>(hsb, Wcat, bq, bk, bv, Qb, Kb, Vtb);
    attn_k<<<dim3(8, 96), blk, 0, stream>>>(Qb, Kb, Vtb, maskp, Ctx);
    gemm_out_k<<<dim3(8 * 8 * 6), blk, 0, stream>>>(Ctx, Wot, bo, hs, Xb);
    ln_k<<<dim3(8192), blk, 0, stream>>>(Xb, lng, lnb, out);
  } else {
    bf16* Qb  = (bf16*)p; p += (size_t)1024 * 768 * 2;
    bf16* Kb  = (bf16*)p; p += (size_t)1024 * 768 * 2;
    bf16* Vtb = (bf16*)p; p += (size_t)1024 * 768 * 2;
    bf16* Ctx = (bf16*)p; p += (size_t)1024 * 768 * 2;
    float* Xb = (float*)p; p += (size_t)1024 * 768 * 4;

    for (int b = 0; b < 8; ++b) {
      const bf16* hsb_b = hsb + (size_t)b * 1024 * 768;
      const float* hs_b = hs + (size_t)b * 1024 * 768;
      float* outb = out + (size_t)b * 1024 * 768;
      gemm_qkv_k<<<dim3(8 * 1 * 18), blk, 0, stream>>>(hsb_b, Wcat, bq, bk, bv, Qb, Kb, Vtb);
      attn_k<<<dim3(8, 12), blk, 0, stream>>>(Qb, Kb, Vtb, maskp + b * 12, Ctx);
      gemm_out_k<<<dim3(8 * 1 * 6), blk, 0, stream>>>(Ctx, Wot, bo, hs_b, Xb);
      ln_k<<<dim3(1024), blk, 0, stream>>>(Xb, lng, lnb, outb);
    }
  }
}

// Round 10
// 249.569 us; speedup vs baseline: 1.2866x; 1.1454x over previous
//
#include <hip/hip_runtime.h>

typedef __bf16 bf16;
typedef __bf16 bf16x4_t __attribute__((ext_vector_type(4)));
typedef __bf16 bf16x8 __attribute__((ext_vector_type(8)));
typedef float  f32x4  __attribute__((ext_vector_type(4)));

__device__ __forceinline__ void async16(const void* g, void* l) {
  __builtin_amdgcn_global_load_lds(
      (__attribute__((address_space(1))) void*)(g),
      (__attribute__((address_space(3))) void*)(l), 16, 0, 0);
}

__device__ __forceinline__ f32x4 mfma16(bf16x8 a, bf16x8 b, f32x4 c) {
  return __builtin_amdgcn_mfma_f32_16x16x32_bf16(a, b, c, 0, 0, 0);
}

// ---------------- hs f32 -> bf16 (float4 streaming) ---------------------------
__global__ __launch_bounds__(256) void cvt_hs_k(const float* __restrict__ src,
                                                bf16* __restrict__ dst, int n) {
  int i = (blockIdx.x * 256 + threadIdx.x) * 4;
  if (i + 3 < n) {
    float4 v = *(const float4*)(src + i);
    dst[i]     = (bf16)v.x;
    dst[i + 1] = (bf16)v.y;
    dst[i + 2] = (bf16)v.z;
    dst[i + 3] = (bf16)v.w;
  } else {
    for (int j = 0; j < 4 && i + j < n; ++j) dst[i + j] = (bf16)src[i + j];
  }
}

// ---------------- 4 weight transposes in one dispatch (z selects) -------------
__global__ __launch_bounds__(256) void transpose4_k(
    const float* __restrict__ s0, const float* __restrict__ s1,
    const float* __restrict__ s2, const float* __restrict__ s3,
    bf16* __restrict__ d0, bf16* __restrict__ d1,
    bf16* __restrict__ d2, bf16* __restrict__ d3) {
  __shared__ bf16 tile[32][33];
  int z = blockIdx.z;
  const float* in = (z == 0) ? s0 : (z == 1) ? s1 : (z == 2) ? s2 : s3;
  bf16* out       = (z == 0) ? d0 : (z == 1) ? d1 : (z == 2) ? d2 : d3;
  int c0 = blockIdx.x * 32, r0 = blockIdx.y * 32;
  int t = threadIdx.x;
#pragma unroll
  for (int i = 0; i < 4; ++i) {
    int idx = t + i * 256;
    int r = idx >> 5, c = idx & 31;
    tile[r][c] = (bf16)in[(size_t)(r0 + r) * 768 + (c0 + c)];
  }
  __syncthreads();
#pragma unroll
  for (int i = 0; i < 4; ++i) {
    int idx = t + i * 256;
    int r = idx >> 5, c = idx & 31;
    out[(size_t)(c0 + r) * 768 + (r0 + c)] = tile[c][r];
  }
}

// ---------------- router stage 1: float4 partial sums over 64 rows of S -------
__global__ __launch_bounds__(256) void router_partial_k(const float* __restrict__ hs,
                                                        float* __restrict__ partial) {
  int b = blockIdx.x, g = blockIdx.y, t = threadIdx.x;
  if (t >= 192) return;
  const float* p = hs + ((size_t)b * 1024 + g * 64) * 768 + t * 4;
  float4 a = {0.f, 0.f, 0.f, 0.f};
  for (int s = 0; s < 64; ++s) {
    float4 v = *(const float4*)(p + (size_t)s * 768);
    a.x += v.x; a.y += v.y; a.z += v.z; a.w += v.w;
  }
  *(float4*)(partial + ((size_t)b * 16 + g) * 768 + t * 4) = a;
}

// ---------------- router stage 2: f32 mean -> logits -> top-6 mask ------------
__global__ __launch_bounds__(256) void router_final_k(const float* __restrict__ Wr,
                                                      const float* __restrict__ br,
                                                      const float* __restrict__ partial,
                                                      float* __restrict__ mask) {
  int b = blockIdx.x, t = threadIdx.x;
  __shared__ float mean_s[768];
  __shared__ float lg[12];
  for (int c = t; c < 768; c += 256) {
    float a = 0.f;
    for (int g = 0; g < 16; ++g) a += partial[((size_t)b * 16 + g) * 768 + c];
    mean_s[c] = a * (1.0f / 1024.0f);
  }
  __syncthreads();
  if (t < 12) {
    float a = br[t];
    for (int c = 0; c < 768; ++c) a += mean_s[c] * Wr[c * 12 + t];
    lg[t] = a;
  }
  __syncthreads();
  if (t == 0) {
    unsigned chosen = 0;
    for (int j = 0; j < 6; ++j) {
      int bi = -1; float bv = -1e30f;
      for (int h = 0; h < 12; ++h)
        if (!((chosen >> h) & 1) && lg[h] > bv) { bv = lg[h]; bi = h; }
      chosen |= 1u << bi;
    }
    for (int h = 0; h < 12; ++h) mask[b * 12 + h] = ((chosen >> h) & 1) ? 1.f : 0.f;
  }
}

// ------- fused QKV GEMM: BK=64, swizzled LDS, hoisted addresses ---------------
__global__ __launch_bounds__(256, 3) void gemm_qkv_k(
    const bf16* __restrict__ X, const bf16* __restrict__ Wcat,
    const float* __restrict__ bq, const float* __restrict__ bk, const float* __restrict__ bv,
    bf16* __restrict__ Qo, bf16* __restrict__ Ko, bf16* __restrict__ Vto) {
  __shared__ __align__(16) bf16 Al[128 * 64];
  __shared__ __align__(16) bf16 Bl[128 * 64];
  int bid = blockIdx.x;
  int xcd = bid & 7, idx = bid >> 3;
  int nt = idx % 18, mt8 = idx / 18;
  int m0 = (mt8 * 8 + xcd) * 128;
  int n0 = nt * 128;
  int z = nt / 6;
  int nb0 = n0 - z * 768;
  const float* bia = (z == 0) ? bq : (z == 1) ? bk : bv;
  int t = threadIdx.x, w = t >> 6, lane = t & 63, lrow = lane & 15, quad = lane >> 4;
  int wm = (w >> 1) * 64, wn = (w & 1) * 64;

  // --- loop-invariant staging pointers (chunk swizzle is i/k-invariant) ---
  int srow = t >> 3;                        // 0..31 within i-group
  int sch  = (t & 7) ^ (srow & 7);          // swizzled chunk
  const bf16* aptr[4];
  const bf16* bptr[4];
#pragma unroll
  for (int i = 0; i < 4; ++i) {
    aptr[i] = X    + (size_t)(m0 + i * 32 + srow) * 768 + sch * 8;
    bptr[i] = Wcat + (size_t)(n0 + i * 32 + srow) * 768 + sch * 8;
  }

  // --- loop-invariant LDS read bases (i enters as immediate offset) ---
  int ra_base = wm + lrow, rb_base = wn + lrow;
  const bf16* baA[2];
  const bf16* baB[2];
#pragma unroll
  for (int ks = 0; ks < 2; ++ks) {
    baA[ks] = &Al[ra_base * 64 + (((ks * 4 + quad) ^ (ra_base & 7)) * 8)];
    baB[ks] = &Bl[rb_base * 64 + (((ks * 4 + quad) ^ (rb_base & 7)) * 8)];
  }

  f32x4 acc[4][4];
#pragma unroll
  for (int a = 0; a < 4; ++a)
#pragma unroll
    for (int b = 0; b < 4; ++b) acc[a][b] = (f32x4){0.f, 0.f, 0.f, 0.f};

  for (int k0 = 0; k0 < 768; k0 += 64) {
#pragma unroll
    for (int i = 0; i < 4; ++i) {
      async16(aptr[i], &Al[(i * 256 + t) * 8]);
      aptr[i] += 64;
    }
#pragma unroll
    for (int i = 0; i < 4; ++i) {
      async16(bptr[i], &Bl[(i * 256 + t) * 8]);
      bptr[i] += 64;
    }
    __syncthreads();
    bf16x8 af[2][4], bfr[2][4];
#pragma unroll
    for (int ks = 0; ks < 2; ++ks)
#pragma unroll
      for (int i = 0; i < 4; ++i) {
        af[ks][i]  = *(const bf16x8*)(baA[ks] + i * 1024);  // +2048B imm
        bfr[ks][i] = *(const bf16x8*)(baB[ks] + i * 1024);
      }
#pragma unroll
    for (int ks = 0; ks < 2; ++ks)
#pragma unroll
      for (int mt = 0; mt < 4; ++mt)
#pragma unroll
        for (int nt2 = 0; nt2 < 4; ++nt2)
          acc[mt][nt2] = mfma16(af[ks][mt], bfr[ks][nt2], acc[mt][nt2]);
    __syncthreads();
  }

  float biasv[4];
#pragma unroll
  for (int nt2 = 0; nt2 < 4; ++nt2) biasv[nt2] = bia[nb0 + wn + nt2 * 16 + lrow];

  if (z == 2) {
    // V: packed transposed store — lane's 4 acc values are s-consecutive
#pragma unroll
    for (int mt = 0; mt < 4; ++mt)
#pragma unroll
      for (int nt2 = 0; nt2 < 4; ++nt2) {
        int s_base = m0 + wm + mt * 16 + quad * 4;
        int bb = s_base >> 10, s = s_base & 1023;
        int nl = nb0 + wn + nt2 * 16 + lrow;
        int h = nl >> 6, d = nl & 63;
        bf16x4_t pk;
#pragma unroll
        for (int r = 0; r < 4; ++r) pk[r] = (bf16)(acc[mt][nt2][r] + biasv[nt2]);
        *(bf16x4_t*)&Vto[(((size_t)bb * 12 + h) * 64 + d) * 1024 + s] = pk;
      }
  } else {
    bf16* Out = (z == 0) ? Qo : Ko;
#pragma unroll
    for (int mt = 0; mt < 4; ++mt)
#pragma unroll
      for (int nt2 = 0; nt2 < 4; ++nt2)
#pragma unroll
        for (int r = 0; r < 4; ++r) {
          int m = m0 + wm + mt * 16 + quad * 4 + r;
          int nl = nb0 + wn + nt2 * 16 + lrow;
          int bb = m >> 10, s = m & 1023, h = nl >> 6, d = nl & 63;
          Out[(((size_t)bb * 12 + h) * 1024 + s) * 64 + d] =
              (bf16)(acc[mt][nt2][r] + biasv[nt2]);
        }
  }
}

// ---------------- flash attention, Q-tile=128, XOR-swizzled LDS ---------------
__global__ __launch_bounds__(256) void attn_k(
    const bf16* __restrict__ Q, const bf16* __restrict__ K, const bf16* __restrict__ Vt,
    const float* __restrict__ mask, bf16* __restrict__ ctx) {
  int qt = blockIdx.x, bh = blockIdx.y;
  int b = bh / 12, h = bh % 12;
  int t = threadIdx.x, w = t >> 6, lane = t & 63, lrow = lane & 15, quad = lane >> 4;

  if (mask[bh] == 0.f) {
    for (int i = t; i < 4096; i += 256) {
      int r = i >> 5, c = i & 31;
      size_t e = ((size_t)(b * 1024 + qt * 128 + r)) * 768 + h * 64;
      ((unsigned*)ctx)[e / 2 + c] = 0u;
    }
    return;
  }

  __shared__ __align__(16) bf16 K_lds[128 * 64];
  __shared__ __align__(16) bf16 V_lds[64 * 128];
  __shared__ __align__(16) bf16 P_lds[4][32 * 136];

  const bf16* Qh = Q  + (size_t)bh * 65536;
  const bf16* Kh = K  + (size_t)bh * 65536;
  const bf16* Vh = Vt + (size_t)bh * 65536;

  bf16x8 qf[2][2];
#pragma unroll
  for (int mt = 0; mt < 2; ++mt)
#pragma unroll
    for (int ks = 0; ks < 2; ++ks)
      qf[mt][ks] = *(const bf16x8*)&Qh[(size_t)(qt * 128 + w * 32 + mt * 16 + lrow) * 64 + ks * 32 + quad * 8];

  f32x4 o_acc[2][4];
  float m_i[2][4], l_i[2][4];
#pragma unroll
  for (int mt = 0; mt < 2; ++mt) {
#pragma unroll
    for (int dt = 0; dt < 4; ++dt) o_acc[mt][dt] = (f32x4){0.f, 0.f, 0.f, 0.f};
#pragma unroll
    for (int r = 0; r < 4; ++r) { m_i[mt][r] = -INFINITY; l_i[mt][r] = 0.f; }
  }

  for (int kt = 0; kt < 8; ++kt) {
#pragma unroll
    for (int i = 0; i < 4; ++i) {
      int c = i * 256 + t;
      int r = c >> 3, ch = (c & 7) ^ (r & 7);
      async16(Kh + (size_t)kt * 8192 + r * 64 + ch * 8, &K_lds[c * 8]);
    }
#pragma unroll
    for (int i = 0; i < 4; ++i) {
      int c = i * 256 + t;
      int r = c >> 4, ch = (c & 15) ^ (r & 7);
      async16(Vh + (size_t)r * 1024 + kt * 128 + ch * 8, &V_lds[c * 8]);
    }
    __syncthreads();

    f32x4 s_acc[2][8];
#pragma unroll
    for (int mt = 0; mt < 2; ++mt)
#pragma unroll
      for (int nt = 0; nt < 8; ++nt) s_acc[mt][nt] = (f32x4){0.f, 0.f, 0.f, 0.f};
#pragma unroll
    for (int nt = 0; nt < 8; ++nt) {
      int rb = nt * 16 + lrow;
#pragma unroll
      for (int ks = 0; ks < 2; ++ks) {
        bf16x8 kf = *(const bf16x8*)&K_lds[rb * 64 + (((ks * 4 + quad) ^ (rb & 7)) * 8)];
        s_acc[0][nt] = mfma16(qf[0][ks], kf, s_acc[0][nt]);
        s_acc[1][nt] = mfma16(qf[1][ks], kf, s_acc[1][nt]);
      }
    }
#pragma unroll
    for (int mt = 0; mt < 2; ++mt)
#pragma unroll
      for (int nt = 0; nt < 8; ++nt) s_acc[mt][nt] = s_acc[mt][nt] * 0.125f;

#pragma unroll
    for (int mt = 0; mt < 2; ++mt) {
#pragma unroll
      for (int r = 0; r < 4; ++r) {
        float mx = s_acc[mt][0][r];
#pragma unroll
        for (int nt = 1; nt < 8; ++nt) mx = fmaxf(mx, s_acc[mt][nt][r]);
        mx = fmaxf(mx, __shfl_xor(mx, 1));
        mx = fmaxf(mx, __shfl_xor(mx, 2));
        mx = fmaxf(mx, __shfl_xor(mx, 4));
        mx = fmaxf(mx, __shfl_xor(mx, 8));
        float mold = m_i[mt][r];
        float mnew = fmaxf(mold, mx);
        float alpha = __expf(mold - mnew);
        m_i[mt][r] = mnew;
        float rs = 0.f;
#pragma unroll
        for (int nt = 0; nt < 8; ++nt) {
          float pv = __expf(s_acc[mt][nt][r] - mnew);
          rs += pv;
          P_lds[w][(mt * 16 + quad * 4 + r) * 136 + nt * 16 + lrow] = (bf16)pv;
        }
        rs += __shfl_xor(rs, 1);
        rs += __shfl_xor(rs, 2);
        rs += __shfl_xor(rs, 4);
        rs += __shfl_xor(rs, 8);
        l_i[mt][r] = l_i[mt][r] * alpha + rs;
#pragma unroll
        for (int dt = 0; dt < 4; ++dt) o_acc[mt][dt][r] *= alpha;
      }
    }
    __syncthreads();

#pragma unroll
    for (int dt = 0; dt < 4; ++dt) {
      int rv = dt * 16 + lrow;
#pragma unroll
      for (int ks = 0; ks < 4; ++ks) {
        bf16x8 vf = *(const bf16x8*)&V_lds[rv * 128 + (((ks * 4 + quad) ^ (rv & 7)) * 8)];
#pragma unroll
        for (int mt = 0; mt < 2; ++mt) {
          bf16x8 pf = *(const bf16x8*)&P_lds[w][(mt * 16 + lrow) * 136 + ks * 32 + quad * 8];
          o_acc[mt][dt] = mfma16(pf, vf, o_acc[mt][dt]);
        }
      }
    }
    __syncthreads();
  }

#pragma unroll
  for (int mt = 0; mt < 2; ++mt)
#pragma unroll
    for (int r = 0; r < 4; ++r) {
      float inv = 1.0f / l_i[mt][r];
      int s = qt * 128 + w * 32 + mt * 16 + quad * 4 + r;
#pragma unroll
      for (int dt = 0; dt < 4; ++dt) {
        int d = dt * 16 + lrow;
        ctx[((size_t)(b * 1024 + s)) * 768 + h * 64 + d] = (bf16)(o_acc[mt][dt][r] * inv);
      }
    }
}

// ------- out-proj GEMM: BK=64, swizzled LDS, hoisted addresses ----------------
__global__ __launch_bounds__(256, 3) void gemm_out_k(
    const bf16* __restrict__ Cx, const bf16* __restrict__ Wot,
    const float* __restrict__ bo, const float* __restrict__ res,
    float* __restrict__ xo) {
  __shared__ __align__(16) bf16 Al[128 * 64];
  __shared__ __align__(16) bf16 Bl[128 * 64];
  int bid = blockIdx.x;
  int xcd = bid & 7, idx = bid >> 3;
  int nt = idx % 6, mt8 = idx / 6;
  int m0 = (mt8 * 8 + xcd) * 128;
  int n0 = nt * 128;
  int t = threadIdx.x, w = t >> 6, lane = t & 63, lrow = lane & 15, quad = lane >> 4;
  int wm = (w >> 1) * 64, wn = (w & 1) * 64;

  int srow = t >> 3;
  int sch  = (t & 7) ^ (srow & 7);
  const bf16* aptr[4];
  const bf16* bptr[4];
#pragma unroll
  for (int i = 0; i < 4; ++i) {
    aptr[i] = Cx  + (size_t)(m0 + i * 32 + srow) * 768 + sch * 8;
    bptr[i] = Wot + (size_t)(n0 + i * 32 + srow) * 768 + sch * 8;
  }
  int ra_base = wm + lrow, rb_base = wn + lrow;
  const bf16* baA[2];
  const bf16* baB[2];
#pragma unroll
  for (int ks = 0; ks < 2; ++ks) {
    baA[ks] = &Al[ra_base * 64 + (((ks * 4 + quad) ^ (ra_base & 7)) * 8)];
    baB[ks] = &Bl[rb_base * 64 + (((ks * 4 + quad) ^ (rb_base & 7)) * 8)];
  }

  f32x4 acc[4][4];
#pragma unroll
  for (int a = 0; a < 4; ++a)
#pragma unroll
    for (int b = 0; b < 4; ++b) acc[a][b] = (f32x4){0.f, 0.f, 0.f, 0.f};

  for (int k0 = 0; k0 < 768; k0 += 64) {
#pragma unroll
    for (int i = 0; i < 4; ++i) {
      async16(aptr[i], &Al[(i * 256 + t) * 8]);
      aptr[i] += 64;
    }
#pragma unroll
    for (int i = 0; i < 4; ++i) {
      async16(bptr[i], &Bl[(i * 256 + t) * 8]);
      bptr[i] += 64;
    }
    __syncthreads();
    bf16x8 af[2][4], bfr[2][4];
#pragma unroll
    for (int ks = 0; ks < 2; ++ks)
#pragma unroll
      for (int i = 0; i < 4; ++i) {
        af[ks][i]  = *(const bf16x8*)(baA[ks] + i * 1024);
        bfr[ks][i] = *(const bf16x8*)(baB[ks] + i * 1024);
      }
#pragma unroll
    for (int ks = 0; ks < 2; ++ks)
#pragma unroll
      for (int mt = 0; mt < 4; ++mt)
#pragma unroll
        for (int nt2 = 0; nt2 < 4; ++nt2)
          acc[mt][nt2] = mfma16(af[ks][mt], bfr[ks][nt2], acc[mt][nt2]);
    __syncthreads();
  }

  float biasv[4];
#pragma unroll
  for (int nt2 = 0; nt2 < 4; ++nt2) biasv[nt2] = bo[n0 + wn + nt2 * 16 + lrow];

#pragma unroll
  for (int mt = 0; mt < 4; ++mt)
#pragma unroll
    for (int nt2 = 0; nt2 < 4; ++nt2)
#pragma unroll
      for (int r = 0; r < 4; ++r) {
        int m = m0 + wm + mt * 16 + quad * 4 + r;
        int n = n0 + wn + nt2 * 16 + lrow;
        xo[(size_t)m * 768 + n] = acc[mt][nt2][r] + biasv[nt2] + res[(size_t)m * 768 + n];
      }
}

// ---------------- LayerNorm over hid=768 per row (f32 in, f32 out) ------------
__global__ __launch_bounds__(256) void ln_k(const float* __restrict__ x,
                                            const float* __restrict__ g,
                                            const float* __restrict__ be,
                                            float* __restrict__ out) {
  int row = blockIdx.x, t = threadIdx.x;
  const float* xr = x + (size_t)row * 768;
  float v0 = xr[t], v1 = xr[t + 256], v2 = xr[t + 512];
  float s = v0 + v1 + v2;
  float s2 = v0 * v0 + v1 * v1 + v2 * v2;
#pragma unroll
  for (int off = 32; off > 0; off >>= 1) {
    s  += __shfl_down(s, off);
    s2 += __shfl_down(s2, off);
  }
  __shared__ float red[8];
  if ((t & 63) == 0) { red[(t >> 6) * 2] = s; red[(t >> 6) * 2 + 1] = s2; }
  __syncthreads();
  if (t == 0) {
    float a = 0.f, b2 = 0.f;
    for (int i = 0; i < 4; ++i) { a += red[2 * i]; b2 += red[2 * i + 1]; }
    float mu = a * (1.0f / 768.0f);
    float var = b2 * (1.0f / 768.0f) - mu * mu;
    red[0] = mu;
    red[1] = rsqrtf(var + 1e-12f);
  }
  __syncthreads();
  float mu = red[0], rs = red[1];
  out[(size_t)row * 768 + t]       = (v0 - mu) * rs * g[t]       + be[t];
  out[(size_t)row * 768 + t + 256] = (v1 - mu) * rs * g[t + 256] + be[t + 256];
  out[(size_t)row * 768 + t + 512] = (v2 - mu) * rs * g[t + 512] + be[t + 512];
}

// ---------------- host launcher ----------------------------------------------
extern "C" void kernel_launch(void* const* d_in, const int* in_sizes, int n_in,
                              void* d_out, int out_size, void* d_ws, size_t ws_size,
                              hipStream_t stream) {
  const float* hs  = (const float*)d_in[0];
  const float* Wq  = (const float*)d_in[1];
  const float* bq  = (const float*)d_in[2];
  const float* Wk  = (const float*)d_in[3];
  const float* bk  = (const float*)d_in[4];
  const float* Wv  = (const float*)d_in[5];
  const float* bv  = (const float*)d_in[6];
  const float* Wr  = (const float*)d_in[7];
  const float* br  = (const float*)d_in[8];
  const float* Wo  = (const float*)d_in[9];
  const float* bo  = (const float*)d_in[10];
  const float* lng = (const float*)d_in[11];
  const float* lnb = (const float*)d_in[12];
  float* out = (float*)d_out;
  dim3 blk(256);

  // ---- workspace layout ----
  char* p = (char*)d_ws;
  float* maskp   = (float*)p; p += 512;
  float* partial = (float*)p; p += (size_t)8 * 16 * 768 * 4;   // 384 KB
  bf16* hsb  = (bf16*)p; p += (size_t)8192 * 768 * 2;          // 12.6 MB
  bf16* Wcat = (bf16*)p; p += (size_t)2304 * 768 * 2;          // 3.5 MB
  bf16* Wot  = (bf16*)p; p += (size_t)768 * 768 * 2;           // 1.2 MB

  cvt_hs_k<<<dim3(6144), blk, 0, stream>>>(hs, hsb, 6291456);
  transpose4_k<<<dim3(24, 24, 4), blk, 0, stream>>>(
      Wq, Wk, Wv, Wo, Wcat, Wcat + 768 * 768, Wcat + 1536 * 768, Wot);
  router_partial_k<<<dim3(8, 16), blk, 0, stream>>>(hs, partial);
  router_final_k<<<dim3(8), blk, 0, stream>>>(Wr, br, partial, maskp);

  size_t used_common = (size_t)(p - (char*)d_ws);
  size_t need_big = used_common + 3 * (size_t)8192 * 768 * 2;

  if (ws_size >= need_big) {
    char* qk_base = p;
    bf16* Qb  = (bf16*)p; p += (size_t)8192 * 768 * 2;
    bf16* Kb  = (bf16*)p; p += (size_t)8192 * 768 * 2;
    bf16* Vtb = (bf16*)p;
    float* Xb = (float*)qk_base;   // aliases Qb+Kb (dead after attn)
    bf16* Ctx = (bf16*)d_out;      // parks in d_out; ln_k overwrites all

    gemm_qkv_k<<<dim3(8 * 8 * 18), blk, 0, stream>>>(hsb, Wcat, bq, bk, bv, Qb, Kb, Vtb);
    attn_k<<<dim3(8, 96), blk, 0, stream>>>(Qb, Kb, Vtb, maskp, Ctx);
    gemm_out_k<<<dim3(8 * 8 * 6), blk, 0, stream>>>(Ctx, Wot, bo, hs, Xb);
    ln_k<<<dim3(8192), blk, 0, stream>>>(Xb, lng, lnb, out);
  } else {
    bf16* Qb  = (bf16*)p; p += (size_t)1024 * 768 * 2;
    bf16* Kb  = (bf16*)p; p += (size_t)1024 * 768 * 2;
    bf16* Vtb = (bf16*)p; p += (size_t)1024 * 768 * 2;
    bf16* Ctx = (bf16*)p; p += (size_t)1024 * 768 * 2;
    float* Xb = (float*)p; p += (size_t)1024 * 768 * 4;

    for (int b = 0; b < 8; ++b) {
      const bf16* hsb_b = hsb + (size_t)b * 1024 * 768;
      const float* hs_b = hs + (size_t)b * 1024 * 768;
      float* outb = out + (size_t)b * 1024 * 768;
      gemm_qkv_k<<<dim3(8 * 1 * 18), blk, 0, stream>>>(hsb_b, Wcat, bq, bk, bv, Qb, Kb, Vtb);
      attn_k<<<dim3(8, 12), blk, 0, stream>>>(Qb, Kb, Vtb, maskp + b * 12, Ctx);
      gemm_out_k<<<dim3(8 * 1 * 6), blk, 0, stream>>>(Ctx, Wot, bo, hs_b, Xb);
      ln_k<<<dim3(1024), blk, 0, stream>>>(Xb, lng, lnb, outb);
    }
  }
}